// Round 7
// baseline (206.860 us; speedup 1.0000x reference)
//
#include <hip/hip_runtime.h>

// VectorQuantizer forward: N=131072 rows of D=64 vs K=1024 codes.
// Outputs flat fp32: [quantized_st (N*D), loss (1), indices-as-float (N)].
//
// Exactness scheme (validated round 6, absmax 0):
//  - vq_main: bf16 hi/lo split MFMA of g[k] = e2[k] - 2*dot. Per row, the
//    EXACT global top-4 (value,idx) is computed. Classification by the
//    validated MARGIN=5e-5 window around the best:
//      * 1 in-window              -> fast path (strict gap: order-independent)
//      * 2-3 in-window, no hazard -> inline exact re-check of candidates only
//      * hazards -> full cleanup: 4th in-window, two in-window candidates from
//        same m-lane, or x2>=120
//  - vq_cleanup: full exact re-scan, hazard rows only.
//
// Round 7: WAVE DESYNC. R0-R6 forensics: delivery exonerated (R4 cut vmem 5x
// -> null; R5 doubled -> +15%), VALU exonerated (R6 +15pts busy -> +4us),
// occupancy exonerated (R5 2.2x -> worse). Remaining shared property: all
// waves run the SAME tile in lockstep -> synchronized stall/compute bursts,
// pipes at ~25% duty. Fix: per-wave tile-order rotation t=(tt+wv*8)&31 (tiles
// independent, no barriers; top-2-by-value + strict-gap fast path + exact
// re-rank paths are visitation-order independent) + setprio(1) around the
// MFMA cluster (staggered phases give the arbiter role diversity; m191).

#define NROWS 131072
#define DIM 64
#define KCODES 1024
#define MARGIN 5e-5f
#define X2_GUARD 120.0f
#define LOSS_SCALE (1.25f / ((float)NROWS * (float)DIM))
#define PADID (1 << 20)

typedef short bf16x8 __attribute__((ext_vector_type(8)));
typedef float f32x4 __attribute__((ext_vector_type(4)));

__device__ __forceinline__ short f2bf(float f) {
    unsigned u = __float_as_uint(f);
    u += 0x7FFF + ((u >> 16) & 1);   // RNE
    return (short)(u >> 16);
}
__device__ __forceinline__ float bf2f(short h) {
    return __uint_as_float(((unsigned)(unsigned short)h) << 16);
}

// Per code k: e2[k] by sequential fmaf (bit-pattern the exact paths rely on),
// plus bf16 hi/lo split of (-2*w) stored in MFMA B-frag order:
//   short index = ((((t*2+ct)*2+kc)*4+q)*16 + m)*8 + j
//   where k = t*32 + ct*16 + m, d = kc*32 + q*8 + j.
// Thread k==0 also zeroes loss + flag counter.
__global__ __launch_bounds__(256) void prep_w(const float* __restrict__ w,
                                              float* __restrict__ e2,
                                              short* __restrict__ w_hi,
                                              short* __restrict__ w_lo,
                                              float* __restrict__ out_loss,
                                              unsigned* __restrict__ flag_cnt) {
    int k = blockIdx.x * blockDim.x + threadIdx.x;
    if (k == 0) { *out_loss = 0.0f; *flag_cnt = 0u; }
    if (k >= KCODES) return;
    const float* wk = w + (size_t)k * DIM;
    float r[DIM];
#pragma unroll
    for (int i = 0; i < DIM / 4; ++i) *(float4*)&r[4 * i] = *(const float4*)(wk + 4 * i);
    float s = 0.f;
#pragma unroll
    for (int d = 0; d < DIM; ++d) s = fmaf(r[d], r[d], s);
    e2[k] = s;

    const int t = k >> 5, ct = (k >> 4) & 1, m = k & 15;
#pragma unroll
    for (int kc = 0; kc < 2; ++kc)
#pragma unroll
        for (int q = 0; q < 4; ++q) {
            bf16x8 hv, lv;
#pragma unroll
            for (int j = 0; j < 8; ++j) {
                float f = -2.0f * r[kc * 32 + q * 8 + j];   // exact scale
                short h = f2bf(f);
                hv[j] = h;
                lv[j] = f2bf(f - bf2f(h));
            }
            size_t fo = ((size_t)(((t * 2 + ct) * 2 + kc) * 4 + q) * 16 + m) * 8;
            *(bf16x8*)(w_hi + fo) = hv;
            *(bf16x8*)(w_lo + fo) = lv;
        }
}

// compare-exchange / min-pair under (value, idx) lexicographic order
#define MINPAIR(av, ai, bv, bi)                                   \
    { bool tk_ = (bv < av) || (bv == av && bi < ai);              \
      av = tk_ ? bv : av; ai = tk_ ? bi : ai; }
#define CEX(xv, xi, yv, yi)                                       \
    { bool tk_ = (yv < xv) || (yv == xv && yi < xi);              \
      float tv_ = xv; int ti_ = xi;                               \
      xv = tk_ ? yv : xv; xi = tk_ ? yi : xi;                     \
      yv = tk_ ? tv_ : yv; yi = tk_ ? ti_ : yi; }

// Block: 4 waves x 32 rows = 128 rows. No LDS/barriers in the K-loop; B-frags
// are direct global b128 loads. Waves scan tiles in rotated order (wv*8
// start) so their load/MFMA/epilogue phases interleave instead of lockstep.
__global__ __launch_bounds__(256, 3) void vq_main(
        const float* __restrict__ x, const float* __restrict__ w,
        const float* __restrict__ e2,
        const short* __restrict__ w_hi, const short* __restrict__ w_lo,
        float* __restrict__ out_q, float* __restrict__ out_loss,
        float* __restrict__ out_idx,
        unsigned* __restrict__ flag_cnt, unsigned* __restrict__ flag_list) {
    const int tid = threadIdx.x;
    const int lane = tid & 63;
    const int wv = tid >> 6;
    const int m = lane & 15;
    const int q = lane >> 4;
    const int block_row0 = blockIdx.x * 128;
    const int wave_row0 = block_row0 + wv * 32;

    __shared__ int sidx[128];
    __shared__ int scnd[128][2];
    __shared__ unsigned char sflg[128];   // 0 fast, 1 two-cand, 2 three-cand, 3 full
    __shared__ float red[4];

    // ---- A operand: 2 rowtiles x 2 k-chunks; A[m][k=q*8+j] ----
    float xa[2][2][8];
#pragma unroll
    for (int rt = 0; rt < 2; ++rt) {
        const float* xr = x + (size_t)(wave_row0 + rt * 16 + m) * DIM + q * 8;
        *(float4*)&xa[rt][0][0] = *(const float4*)(xr);
        *(float4*)&xa[rt][0][4] = *(const float4*)(xr + 4);
        *(float4*)&xa[rt][1][0] = *(const float4*)(xr + 32);
        *(float4*)&xa[rt][1][4] = *(const float4*)(xr + 36);
    }
    bf16x8 ah[2][2], al[2][2];
#pragma unroll
    for (int rt = 0; rt < 2; ++rt)
#pragma unroll
        for (int c = 0; c < 2; ++c)
#pragma unroll
            for (int j = 0; j < 8; ++j) {
                float f = xa[rt][c][j];
                short h = f2bf(f);
                ah[rt][c][j] = h;
                al[rt][c][j] = f2bf(f - bf2f(h));
            }

    float best[2][4], sec[2][4];
    int bidx[2][4], sbix[2][4];
#pragma unroll
    for (int rt = 0; rt < 2; ++rt)
#pragma unroll
        for (int r = 0; r < 4; ++r) {
            best[rt][r] = 3.4e38f;
            sec[rt][r] = 3.4e38f;
            bidx[rt][r] = PADID;
            sbix[rt][r] = PADID;
        }

    // Per-lane B pointers into frag-ordered arrays; tile stride 2048 shorts.
    const short* ph = w_hi + q * 128 + m * 8;
    const short* pl = w_lo + q * 128 + m * 8;
    const float* pe = e2 + m;

    const int t0 = wv * 8;   // wave phase stagger over the 32 tiles
    for (int tt = 0; tt < KCODES / 32; ++tt) {
        const int t = (tt + t0) & (KCODES / 32 - 1);
        bf16x8 bh[2][2], bl[2][2];
#pragma unroll
        for (int ct = 0; ct < 2; ++ct)
#pragma unroll
            for (int kc = 0; kc < 2; ++kc) {
                int off = t * 2048 + (ct * 2 + kc) * 512;
                bh[ct][kc] = *(const bf16x8*)(ph + off);
                bl[ct][kc] = *(const bf16x8*)(pl + off);
            }
        float e2c0 = pe[t * 32];
        float e2c1 = pe[t * 32 + 16];

        __builtin_amdgcn_s_setprio(1);
#pragma unroll
        for (int rt = 0; rt < 2; ++rt)
#pragma unroll
            for (int ct = 0; ct < 2; ++ct) {
                float ei = ct ? e2c1 : e2c0;
                f32x4 a = {ei, ei, ei, ei};
                a = __builtin_amdgcn_mfma_f32_16x16x32_bf16(al[rt][0], bh[ct][0], a, 0, 0, 0);
                a = __builtin_amdgcn_mfma_f32_16x16x32_bf16(ah[rt][0], bl[ct][0], a, 0, 0, 0);
                a = __builtin_amdgcn_mfma_f32_16x16x32_bf16(ah[rt][0], bh[ct][0], a, 0, 0, 0);
                a = __builtin_amdgcn_mfma_f32_16x16x32_bf16(al[rt][1], bh[ct][1], a, 0, 0, 0);
                a = __builtin_amdgcn_mfma_f32_16x16x32_bf16(ah[rt][1], bl[ct][1], a, 0, 0, 0);
                a = __builtin_amdgcn_mfma_f32_16x16x32_bf16(ah[rt][1], bh[ct][1], a, 0, 0, 0);
                int id = t * 32 + ct * 16 + m;
#pragma unroll
                for (int r = 0; r < 4; ++r) {
                    float g = a[r];
                    bool ltb = g < best[rt][r];
                    bool lts = g < sec[rt][r];
                    float nsec = ltb ? best[rt][r] : (lts ? g : sec[rt][r]);
                    int nsid = ltb ? bidx[rt][r] : (lts ? id : sbix[rt][r]);
                    best[rt][r] = ltb ? g : best[rt][r];
                    bidx[rt][r] = ltb ? id : bidx[rt][r];
                    sec[rt][r] = nsec;
                    sbix[rt][r] = nsid;
                }
            }
        __builtin_amdgcn_s_setprio(0);
    }

    // ---- exact global top-4 per row via bitonic 4+4->4 merges over m-lanes ----
#pragma unroll
    for (int rt = 0; rt < 2; ++rt)
#pragma unroll
        for (int r = 0; r < 4; ++r) {
            float v0 = best[rt][r], v1 = sec[rt][r], v2 = 3.4e38f, v3 = 3.4e38f;
            int j0 = bidx[rt][r], j1 = sbix[rt][r], j2 = PADID, j3 = PADID;
#pragma unroll
            for (int off = 1; off < 16; off <<= 1) {
                float b0 = __shfl_xor(v0, off, 64);
                float b1 = __shfl_xor(v1, off, 64);
                float b2 = __shfl_xor(v2, off, 64);
                float b3 = __shfl_xor(v3, off, 64);
                int k0 = __shfl_xor(j0, off, 64);
                int k1 = __shfl_xor(j1, off, 64);
                int k2 = __shfl_xor(j2, off, 64);
                int k3 = __shfl_xor(j3, off, 64);
                // bitonic split: lows = min(a_i, b_{3-i}) == 4 smallest of union
                MINPAIR(v0, j0, b3, k3);
                MINPAIR(v1, j1, b2, k2);
                MINPAIR(v2, j2, b1, k1);
                MINPAIR(v3, j3, b0, k0);
                // sort the bitonic 4-list
                CEX(v0, j0, v2, j2);
                CEX(v1, j1, v3, j3);
                CEX(v0, j0, v1, j1);
                CEX(v2, j2, v3, j3);
            }
            if (m == 0) {
                bool w1 = v1 < v0 + MARGIN;
                bool w2 = v2 < v0 + MARGIN;
                bool w3 = v3 < v0 + MARGIN;
                bool samem = (w1 && ((j0 & 15) == (j1 & 15))) ||
                             (w2 && (((j0 & 15) == (j2 & 15)) ||
                                     ((j1 & 15) == (j2 & 15))));
                int meta;
                if (w3 || samem) meta = 3;
                else if (w2) meta = 2;
                else if (w1) meta = 1;
                else meta = 0;
                int lr = wv * 32 + rt * 16 + q * 4 + r;
                sidx[lr] = j0;
                scnd[lr][0] = j1;
                scnd[lr][1] = j2;
                sflg[lr] = (unsigned char)meta;
                if (meta == 3) {
                    unsigned p = atomicAdd(flag_cnt, 1u);
                    flag_list[p] = (unsigned)(block_row0 + lr);
                }
            }
        }
    __syncthreads();

    // ---- output pass: 2 x 64 rows, 4 threads/row ----
    float lsum = 0.f;
    const int rl = tid >> 2, part = tid & 3;
#pragma unroll
    for (int p = 0; p < 2; ++p) {
        int lr = p * 64 + rl;
        int grow = block_row0 + lr;
        int meta = sflg[lr];
        if (meta == 0) {
            int bi = sidx[lr];
            const float* xs = x + (size_t)grow * DIM + part * 16;
            const float* ws = w + (size_t)bi * DIM + part * 16;
            float* os = out_q + (size_t)grow * DIM + part * 16;
#pragma unroll
            for (int i = 0; i < 4; ++i) {
                float4 xv = *(const float4*)(xs + 4 * i);
                float4 wv4 = *(const float4*)(ws + 4 * i);
                float d0 = wv4.x - xv.x, d1 = wv4.y - xv.y;
                float d2 = wv4.z - xv.z, d3 = wv4.w - xv.w;
                lsum = fmaf(d0, d0, lsum);
                lsum = fmaf(d1, d1, lsum);
                lsum = fmaf(d2, d2, lsum);
                lsum = fmaf(d3, d3, lsum);
                float4 o = {xv.x + d0, xv.y + d1, xv.z + d2, xv.w + d3};
                *(float4*)(os + 4 * i) = o;
            }
            if (part == 0) out_idx[grow] = (float)bi;
        } else if (meta != 3) {
            // inline exact re-check among 2-3 candidates (cleanup numerics)
            int nc = meta + 1;
            int cand = (part == 0) ? sidx[lr]
                     : (part == 1) ? scnd[lr][0] : scnd[lr][1];
            unsigned long long key = ~0ULL;
            float x2v = 0.f;
            if (part < nc) {
                const float* xr = x + (size_t)grow * DIM;
                const float* wr = w + (size_t)cand * DIM;
                float dot = 0.f;
#pragma unroll
                for (int d4 = 0; d4 < 16; ++d4) {
                    float4 xv = *(const float4*)(xr + 4 * d4);
                    float4 wv4 = *(const float4*)(wr + 4 * d4);
                    x2v = fmaf(xv.x, xv.x, x2v);
                    x2v = fmaf(xv.y, xv.y, x2v);
                    x2v = fmaf(xv.z, xv.z, x2v);
                    x2v = fmaf(xv.w, xv.w, x2v);
                    dot = fmaf(xv.x, wv4.x, dot);
                    dot = fmaf(xv.y, wv4.y, dot);
                    dot = fmaf(xv.z, wv4.z, dot);
                    dot = fmaf(xv.w, wv4.w, dot);
                }
                float dist = (x2v + e2[cand]) - 2.0f * dot;
                key = ((unsigned long long)__float_as_uint(dist) << 32) |
                      (unsigned)cand;
            }
            {
                unsigned long long o1 = __shfl_xor(key, 1, 64);
                key = key < o1 ? key : o1;
                unsigned long long o2 = __shfl_xor(key, 2, 64);
                key = key < o2 ? key : o2;
            }
            float x2b = __shfl(x2v, lane & 60, 64);   // part0's x2 (part0<nc)
            if (x2b >= X2_GUARD) {
                if (part == 0) {
                    unsigned pp = atomicAdd(flag_cnt, 1u);
                    flag_list[pp] = (unsigned)grow;
                }
            } else {
                int bi = (int)(unsigned)(key & 0xFFFFFFFFu);
                const float* xs = x + (size_t)grow * DIM + part * 16;
                const float* ws = w + (size_t)bi * DIM + part * 16;
                float* os = out_q + (size_t)grow * DIM + part * 16;
#pragma unroll
                for (int i = 0; i < 4; ++i) {
                    float4 xv = *(const float4*)(xs + 4 * i);
                    float4 wv4 = *(const float4*)(ws + 4 * i);
                    float d0 = wv4.x - xv.x, d1 = wv4.y - xv.y;
                    float d2 = wv4.z - xv.z, d3 = wv4.w - xv.w;
                    lsum = fmaf(d0, d0, lsum);
                    lsum = fmaf(d1, d1, lsum);
                    lsum = fmaf(d2, d2, lsum);
                    lsum = fmaf(d3, d3, lsum);
                    float4 o = {xv.x + d0, xv.y + d1, xv.z + d2, xv.w + d3};
                    *(float4*)(os + 4 * i) = o;
                }
                if (part == 0) out_idx[grow] = (float)bi;
            }
        }
        // meta == 3: cleanup kernel writes this row (incl. its loss term)
    }

    for (int off = 32; off > 0; off >>= 1) lsum += __shfl_down(lsum, off, 64);
    if ((tid & 63) == 0) red[tid >> 6] = lsum;
    __syncthreads();
    if (tid == 0) {
        float s = (red[0] + red[1]) + (red[2] + red[3]);
        atomicAdd(out_loss, s * LOSS_SCALE);
    }
}

// Exact re-scan of flagged rows (bit-exact numerics). Hazard rows only.
#define CH 16
__global__ __launch_bounds__(256) void vq_cleanup(
        const float* __restrict__ x, const float* __restrict__ w,
        const float* __restrict__ e2,
        const unsigned* __restrict__ flag_cnt,
        const unsigned* __restrict__ flag_list,
        float* __restrict__ out_q, float* __restrict__ out_loss,
        float* __restrict__ out_idx) {
    __shared__ float xs[CH][68];
    __shared__ float wt[128][68];
    __shared__ float sx2[CH];
    const int tid = threadIdx.x;
    const int rowsub = tid >> 4;    // 0..15
    const int kslot = tid & 15;
    const unsigned cnt = *flag_cnt;

    for (unsigned base = blockIdx.x * CH; base < cnt; base += gridDim.x * CH) {
        const int nrows = (int)min((unsigned)CH, cnt - base);
        __syncthreads();
        {
            int rr = tid >> 4, sg = tid & 15;
            if (rr < nrows) {
                unsigned grow = flag_list[base + rr];
                *(float4*)&xs[rr][sg * 4] =
                    *(const float4*)(x + (size_t)grow * DIM + sg * 4);
            }
        }
        __syncthreads();
        if (tid < nrows) {
            float s = 0.f;
#pragma unroll
            for (int d = 0; d < DIM; ++d) s = fmaf(xs[tid][d], xs[tid][d], s);
            sx2[tid] = s;
        }

        unsigned long long kmin = ~0ULL;
        for (int tile = 0; tile < KCODES / 128; ++tile) {
            __syncthreads();
#pragma unroll
            for (int i = 0; i < 8; ++i) {
                int f = tid + i * 256;
                int code = f >> 4, sg = f & 15;
                *(float4*)&wt[code][sg * 4] =
                    *(const float4*)(w + (size_t)(tile * 128 + code) * DIM + sg * 4);
            }
            __syncthreads();
            if (rowsub < nrows) {
#pragma unroll
                for (int j = 0; j < 8; ++j) {
                    int cl = j * 16 + kslot;
                    int code = tile * 128 + cl;
                    float dot = 0.f;
#pragma unroll
                    for (int d4 = 0; d4 < 16; ++d4) {
                        float4 wv4 = *(const float4*)&wt[cl][d4 * 4];
                        float4 xv4 = *(const float4*)&xs[rowsub][d4 * 4];
                        dot = fmaf(wv4.x, xv4.x, dot);
                        dot = fmaf(wv4.y, xv4.y, dot);
                        dot = fmaf(wv4.z, xv4.z, dot);
                        dot = fmaf(wv4.w, xv4.w, dot);
                    }
                    float dist = (sx2[rowsub] + e2[code]) - 2.0f * dot;
                    unsigned long long key =
                        ((unsigned long long)__float_as_uint(dist) << 32) |
                        (unsigned)code;
                    kmin = kmin < key ? kmin : key;
                }
            }
        }
#pragma unroll
        for (int off = 1; off < 16; off <<= 1) {
            unsigned long long o = __shfl_xor(kmin, off, 64);
            kmin = kmin < o ? kmin : o;
        }
        if (rowsub < nrows) {
            int bi = (int)(unsigned)(kmin & 0xFFFFFFFFu);
            unsigned grow = flag_list[base + rowsub];
            float4 x4 = *(float4*)&xs[rowsub][kslot * 4];
            float4 w4 = *(const float4*)(w + (size_t)bi * DIM + kslot * 4);
            float d0 = w4.x - x4.x, d1 = w4.y - x4.y;
            float d2 = w4.z - x4.z, d3 = w4.w - x4.w;
            float ls = 0.f;
            ls = fmaf(d0, d0, ls);
            ls = fmaf(d1, d1, ls);
            ls = fmaf(d2, d2, ls);
            ls = fmaf(d3, d3, ls);
            float4 o = {x4.x + d0, x4.y + d1, x4.z + d2, x4.w + d3};
            *(float4*)(out_q + (size_t)grow * DIM + kslot * 4) = o;
            if (kslot == 0) out_idx[grow] = (float)bi;
#pragma unroll
            for (int off = 1; off < 16; off <<= 1)
                ls += __shfl_xor(ls, off, 64);
            if (kslot == 0) atomicAdd(out_loss, ls * LOSS_SCALE);
        }
    }
}

extern "C" void kernel_launch(void* const* d_in, const int* in_sizes, int n_in,
                              void* d_out, int out_size, void* d_ws, size_t ws_size,
                              hipStream_t stream) {
    const float* x = (const float*)d_in[0];   // [N, D]
    const float* w = (const float*)d_in[1];   // [K, D]

    float* out_q    = (float*)d_out;
    float* out_loss = (float*)d_out + (size_t)NROWS * DIM;
    float* out_idx  = out_loss + 1;

    // ws: e2 (4KB) | w_hi frag-order (128KB) | w_lo (128KB) | cnt | list (512KB)
    float* e2 = (float*)d_ws;
    short* w_hi = (short*)(e2 + KCODES);
    short* w_lo = w_hi + (size_t)KCODES * DIM;
    unsigned* cnt = (unsigned*)(w_lo + (size_t)KCODES * DIM);
    unsigned* list = cnt + 1;

    prep_w<<<(KCODES + 255) / 256, 256, 0, stream>>>(w, e2, w_hi, w_lo,
                                                     out_loss, cnt);
    vq_main<<<NROWS / 128, 256, 0, stream>>>(x, w, e2, w_hi, w_lo,
                                             out_q, out_loss, out_idx, cnt, list);
    vq_cleanup<<<256, 256, 0, stream>>>(x, w, e2, cnt, list,
                                        out_q, out_loss, out_idx);
}

// Round 8
// 205.263 us; speedup vs baseline: 1.0078x; 1.0078x over previous
//
#include <hip/hip_runtime.h>

// VectorQuantizer forward: N=131072 rows of D=64 vs K=1024 codes.
// Outputs flat fp32: [quantized_st (N*D), loss (1), indices-as-float (N)].
//
// Exactness scheme (validated round 6, absmax 0):
//  - vq_main: bf16 hi/lo split MFMA of g[k] = e2[k] - 2*dot. Per row, the
//    EXACT global top-4 (value,idx) is computed. Classification by the
//    validated MARGIN=5e-5 window around the best:
//      * 1 in-window              -> fast path (strict gap: order-independent)
//      * 2-3 in-window, no hazard -> inline exact re-check of candidates only
//      * hazards -> full cleanup: 4th in-window, two in-window candidates from
//        same m-lane, or x2>=120
//  - vq_cleanup: full exact re-scan, hazard rows only.
//
// Round 8: BLOCK-LEVEL DESYNC. R7's per-wave rotation failed two ways: on a
// SIMD all resident waves have the same wv -> same rotation (no desync where
// it matters), and it split the block's 4 waves across 4 tiles -> 32KB live
// B-footprint = L1 size -> thrash (main 96->146). Fix: rotate per block-group
// t0=((blockIdx>>8)&3)*8 -- co-resident blocks (b, b+256, b+512 under
// round-robin XCD dispatch) get different phases, desyncing the waves that
// share a SIMD, while each block's 4 waves stay lockstep on one tile so L1
// temporal sharing (the mechanism R4/R7 proved is doing the delivery) is
// preserved. 3 tiles x 8KB = 24KB < 32KB L1. No setprio. Otherwise R6.

#define NROWS 131072
#define DIM 64
#define KCODES 1024
#define MARGIN 5e-5f
#define X2_GUARD 120.0f
#define LOSS_SCALE (1.25f / ((float)NROWS * (float)DIM))
#define PADID (1 << 20)

typedef short bf16x8 __attribute__((ext_vector_type(8)));
typedef float f32x4 __attribute__((ext_vector_type(4)));

__device__ __forceinline__ short f2bf(float f) {
    unsigned u = __float_as_uint(f);
    u += 0x7FFF + ((u >> 16) & 1);   // RNE
    return (short)(u >> 16);
}
__device__ __forceinline__ float bf2f(short h) {
    return __uint_as_float(((unsigned)(unsigned short)h) << 16);
}

// Per code k: e2[k] by sequential fmaf (bit-pattern the exact paths rely on),
// plus bf16 hi/lo split of (-2*w) stored in MFMA B-frag order:
//   short index = ((((t*2+ct)*2+kc)*4+q)*16 + m)*8 + j
//   where k = t*32 + ct*16 + m, d = kc*32 + q*8 + j.
// Thread k==0 also zeroes loss + flag counter.
__global__ __launch_bounds__(256) void prep_w(const float* __restrict__ w,
                                              float* __restrict__ e2,
                                              short* __restrict__ w_hi,
                                              short* __restrict__ w_lo,
                                              float* __restrict__ out_loss,
                                              unsigned* __restrict__ flag_cnt) {
    int k = blockIdx.x * blockDim.x + threadIdx.x;
    if (k == 0) { *out_loss = 0.0f; *flag_cnt = 0u; }
    if (k >= KCODES) return;
    const float* wk = w + (size_t)k * DIM;
    float r[DIM];
#pragma unroll
    for (int i = 0; i < DIM / 4; ++i) *(float4*)&r[4 * i] = *(const float4*)(wk + 4 * i);
    float s = 0.f;
#pragma unroll
    for (int d = 0; d < DIM; ++d) s = fmaf(r[d], r[d], s);
    e2[k] = s;

    const int t = k >> 5, ct = (k >> 4) & 1, m = k & 15;
#pragma unroll
    for (int kc = 0; kc < 2; ++kc)
#pragma unroll
        for (int q = 0; q < 4; ++q) {
            bf16x8 hv, lv;
#pragma unroll
            for (int j = 0; j < 8; ++j) {
                float f = -2.0f * r[kc * 32 + q * 8 + j];   // exact scale
                short h = f2bf(f);
                hv[j] = h;
                lv[j] = f2bf(f - bf2f(h));
            }
            size_t fo = ((size_t)(((t * 2 + ct) * 2 + kc) * 4 + q) * 16 + m) * 8;
            *(bf16x8*)(w_hi + fo) = hv;
            *(bf16x8*)(w_lo + fo) = lv;
        }
}

// compare-exchange / min-pair under (value, idx) lexicographic order
#define MINPAIR(av, ai, bv, bi)                                   \
    { bool tk_ = (bv < av) || (bv == av && bi < ai);              \
      av = tk_ ? bv : av; ai = tk_ ? bi : ai; }
#define CEX(xv, xi, yv, yi)                                       \
    { bool tk_ = (yv < xv) || (yv == xv && yi < xi);              \
      float tv_ = xv; int ti_ = xi;                               \
      xv = tk_ ? yv : xv; xi = tk_ ? yi : xi;                     \
      yv = tk_ ? tv_ : yv; yi = tk_ ? ti_ : yi; }

// Block: 4 waves x 32 rows = 128 rows. No LDS/barriers in the K-loop; B-frags
// are direct global b128 loads. Co-resident blocks scan tiles in rotated
// order (t0 per block-group) so same-SIMD waves interleave phases.
__global__ __launch_bounds__(256, 3) void vq_main(
        const float* __restrict__ x, const float* __restrict__ w,
        const float* __restrict__ e2,
        const short* __restrict__ w_hi, const short* __restrict__ w_lo,
        float* __restrict__ out_q, float* __restrict__ out_loss,
        float* __restrict__ out_idx,
        unsigned* __restrict__ flag_cnt, unsigned* __restrict__ flag_list) {
    const int tid = threadIdx.x;
    const int lane = tid & 63;
    const int wv = tid >> 6;
    const int m = lane & 15;
    const int q = lane >> 4;
    const int block_row0 = blockIdx.x * 128;
    const int wave_row0 = block_row0 + wv * 32;

    __shared__ int sidx[128];
    __shared__ int scnd[128][2];
    __shared__ unsigned char sflg[128];   // 0 fast, 1 two-cand, 2 three-cand, 3 full
    __shared__ float red[4];

    // ---- A operand: 2 rowtiles x 2 k-chunks; A[m][k=q*8+j] ----
    float xa[2][2][8];
#pragma unroll
    for (int rt = 0; rt < 2; ++rt) {
        const float* xr = x + (size_t)(wave_row0 + rt * 16 + m) * DIM + q * 8;
        *(float4*)&xa[rt][0][0] = *(const float4*)(xr);
        *(float4*)&xa[rt][0][4] = *(const float4*)(xr + 4);
        *(float4*)&xa[rt][1][0] = *(const float4*)(xr + 32);
        *(float4*)&xa[rt][1][4] = *(const float4*)(xr + 36);
    }
    bf16x8 ah[2][2], al[2][2];
#pragma unroll
    for (int rt = 0; rt < 2; ++rt)
#pragma unroll
        for (int c = 0; c < 2; ++c)
#pragma unroll
            for (int j = 0; j < 8; ++j) {
                float f = xa[rt][c][j];
                short h = f2bf(f);
                ah[rt][c][j] = h;
                al[rt][c][j] = f2bf(f - bf2f(h));
            }

    float best[2][4], sec[2][4];
    int bidx[2][4], sbix[2][4];
#pragma unroll
    for (int rt = 0; rt < 2; ++rt)
#pragma unroll
        for (int r = 0; r < 4; ++r) {
            best[rt][r] = 3.4e38f;
            sec[rt][r] = 3.4e38f;
            bidx[rt][r] = PADID;
            sbix[rt][r] = PADID;
        }

    // Per-lane B pointers into frag-ordered arrays; tile stride 2048 shorts.
    const short* ph = w_hi + q * 128 + m * 8;
    const short* pl = w_lo + q * 128 + m * 8;
    const float* pe = e2 + m;

    // Block-group tile-phase rotation: co-resident blocks differ in bid>>8
    // (same XCD/CU slot <=> same bid mod 256 under round-robin dispatch).
    const int t0 = ((blockIdx.x >> 8) & 3) * 8;
    for (int tt = 0; tt < KCODES / 32; ++tt) {
        const int t = (tt + t0) & (KCODES / 32 - 1);
        bf16x8 bh[2][2], bl[2][2];
#pragma unroll
        for (int ct = 0; ct < 2; ++ct)
#pragma unroll
            for (int kc = 0; kc < 2; ++kc) {
                int off = t * 2048 + (ct * 2 + kc) * 512;
                bh[ct][kc] = *(const bf16x8*)(ph + off);
                bl[ct][kc] = *(const bf16x8*)(pl + off);
            }
        float e2c0 = pe[t * 32];
        float e2c1 = pe[t * 32 + 16];

#pragma unroll
        for (int rt = 0; rt < 2; ++rt)
#pragma unroll
            for (int ct = 0; ct < 2; ++ct) {
                float ei = ct ? e2c1 : e2c0;
                f32x4 a = {ei, ei, ei, ei};
                a = __builtin_amdgcn_mfma_f32_16x16x32_bf16(al[rt][0], bh[ct][0], a, 0, 0, 0);
                a = __builtin_amdgcn_mfma_f32_16x16x32_bf16(ah[rt][0], bl[ct][0], a, 0, 0, 0);
                a = __builtin_amdgcn_mfma_f32_16x16x32_bf16(ah[rt][0], bh[ct][0], a, 0, 0, 0);
                a = __builtin_amdgcn_mfma_f32_16x16x32_bf16(al[rt][1], bh[ct][1], a, 0, 0, 0);
                a = __builtin_amdgcn_mfma_f32_16x16x32_bf16(ah[rt][1], bl[ct][1], a, 0, 0, 0);
                a = __builtin_amdgcn_mfma_f32_16x16x32_bf16(ah[rt][1], bh[ct][1], a, 0, 0, 0);
                int id = t * 32 + ct * 16 + m;
#pragma unroll
                for (int r = 0; r < 4; ++r) {
                    float g = a[r];
                    bool ltb = g < best[rt][r];
                    bool lts = g < sec[rt][r];
                    float nsec = ltb ? best[rt][r] : (lts ? g : sec[rt][r]);
                    int nsid = ltb ? bidx[rt][r] : (lts ? id : sbix[rt][r]);
                    best[rt][r] = ltb ? g : best[rt][r];
                    bidx[rt][r] = ltb ? id : bidx[rt][r];
                    sec[rt][r] = nsec;
                    sbix[rt][r] = nsid;
                }
            }
    }

    // ---- exact global top-4 per row via bitonic 4+4->4 merges over m-lanes ----
#pragma unroll
    for (int rt = 0; rt < 2; ++rt)
#pragma unroll
        for (int r = 0; r < 4; ++r) {
            float v0 = best[rt][r], v1 = sec[rt][r], v2 = 3.4e38f, v3 = 3.4e38f;
            int j0 = bidx[rt][r], j1 = sbix[rt][r], j2 = PADID, j3 = PADID;
#pragma unroll
            for (int off = 1; off < 16; off <<= 1) {
                float b0 = __shfl_xor(v0, off, 64);
                float b1 = __shfl_xor(v1, off, 64);
                float b2 = __shfl_xor(v2, off, 64);
                float b3 = __shfl_xor(v3, off, 64);
                int k0 = __shfl_xor(j0, off, 64);
                int k1 = __shfl_xor(j1, off, 64);
                int k2 = __shfl_xor(j2, off, 64);
                int k3 = __shfl_xor(j3, off, 64);
                // bitonic split: lows = min(a_i, b_{3-i}) == 4 smallest of union
                MINPAIR(v0, j0, b3, k3);
                MINPAIR(v1, j1, b2, k2);
                MINPAIR(v2, j2, b1, k1);
                MINPAIR(v3, j3, b0, k0);
                // sort the bitonic 4-list
                CEX(v0, j0, v2, j2);
                CEX(v1, j1, v3, j3);
                CEX(v0, j0, v1, j1);
                CEX(v2, j2, v3, j3);
            }
            if (m == 0) {
                bool w1 = v1 < v0 + MARGIN;
                bool w2 = v2 < v0 + MARGIN;
                bool w3 = v3 < v0 + MARGIN;
                bool samem = (w1 && ((j0 & 15) == (j1 & 15))) ||
                             (w2 && (((j0 & 15) == (j2 & 15)) ||
                                     ((j1 & 15) == (j2 & 15))));
                int meta;
                if (w3 || samem) meta = 3;
                else if (w2) meta = 2;
                else if (w1) meta = 1;
                else meta = 0;
                int lr = wv * 32 + rt * 16 + q * 4 + r;
                sidx[lr] = j0;
                scnd[lr][0] = j1;
                scnd[lr][1] = j2;
                sflg[lr] = (unsigned char)meta;
                if (meta == 3) {
                    unsigned p = atomicAdd(flag_cnt, 1u);
                    flag_list[p] = (unsigned)(block_row0 + lr);
                }
            }
        }
    __syncthreads();

    // ---- output pass: 2 x 64 rows, 4 threads/row ----
    float lsum = 0.f;
    const int rl = tid >> 2, part = tid & 3;
#pragma unroll
    for (int p = 0; p < 2; ++p) {
        int lr = p * 64 + rl;
        int grow = block_row0 + lr;
        int meta = sflg[lr];
        if (meta == 0) {
            int bi = sidx[lr];
            const float* xs = x + (size_t)grow * DIM + part * 16;
            const float* ws = w + (size_t)bi * DIM + part * 16;
            float* os = out_q + (size_t)grow * DIM + part * 16;
#pragma unroll
            for (int i = 0; i < 4; ++i) {
                float4 xv = *(const float4*)(xs + 4 * i);
                float4 wv4 = *(const float4*)(ws + 4 * i);
                float d0 = wv4.x - xv.x, d1 = wv4.y - xv.y;
                float d2 = wv4.z - xv.z, d3 = wv4.w - xv.w;
                lsum = fmaf(d0, d0, lsum);
                lsum = fmaf(d1, d1, lsum);
                lsum = fmaf(d2, d2, lsum);
                lsum = fmaf(d3, d3, lsum);
                float4 o = {xv.x + d0, xv.y + d1, xv.z + d2, xv.w + d3};
                *(float4*)(os + 4 * i) = o;
            }
            if (part == 0) out_idx[grow] = (float)bi;
        } else if (meta != 3) {
            // inline exact re-check among 2-3 candidates (cleanup numerics)
            int nc = meta + 1;
            int cand = (part == 0) ? sidx[lr]
                     : (part == 1) ? scnd[lr][0] : scnd[lr][1];
            unsigned long long key = ~0ULL;
            float x2v = 0.f;
            if (part < nc) {
                const float* xr = x + (size_t)grow * DIM;
                const float* wr = w + (size_t)cand * DIM;
                float dot = 0.f;
#pragma unroll
                for (int d4 = 0; d4 < 16; ++d4) {
                    float4 xv = *(const float4*)(xr + 4 * d4);
                    float4 wv4 = *(const float4*)(wr + 4 * d4);
                    x2v = fmaf(xv.x, xv.x, x2v);
                    x2v = fmaf(xv.y, xv.y, x2v);
                    x2v = fmaf(xv.z, xv.z, x2v);
                    x2v = fmaf(xv.w, xv.w, x2v);
                    dot = fmaf(xv.x, wv4.x, dot);
                    dot = fmaf(xv.y, wv4.y, dot);
                    dot = fmaf(xv.z, wv4.z, dot);
                    dot = fmaf(xv.w, wv4.w, dot);
                }
                float dist = (x2v + e2[cand]) - 2.0f * dot;
                key = ((unsigned long long)__float_as_uint(dist) << 32) |
                      (unsigned)cand;
            }
            {
                unsigned long long o1 = __shfl_xor(key, 1, 64);
                key = key < o1 ? key : o1;
                unsigned long long o2 = __shfl_xor(key, 2, 64);
                key = key < o2 ? key : o2;
            }
            float x2b = __shfl(x2v, lane & 60, 64);   // part0's x2 (part0<nc)
            if (x2b >= X2_GUARD) {
                if (part == 0) {
                    unsigned pp = atomicAdd(flag_cnt, 1u);
                    flag_list[pp] = (unsigned)grow;
                }
            } else {
                int bi = (int)(unsigned)(key & 0xFFFFFFFFu);
                const float* xs = x + (size_t)grow * DIM + part * 16;
                const float* ws = w + (size_t)bi * DIM + part * 16;
                float* os = out_q + (size_t)grow * DIM + part * 16;
#pragma unroll
                for (int i = 0; i < 4; ++i) {
                    float4 xv = *(const float4*)(xs + 4 * i);
                    float4 wv4 = *(const float4*)(ws + 4 * i);
                    float d0 = wv4.x - xv.x, d1 = wv4.y - xv.y;
                    float d2 = wv4.z - xv.z, d3 = wv4.w - xv.w;
                    lsum = fmaf(d0, d0, lsum);
                    lsum = fmaf(d1, d1, lsum);
                    lsum = fmaf(d2, d2, lsum);
                    lsum = fmaf(d3, d3, lsum);
                    float4 o = {xv.x + d0, xv.y + d1, xv.z + d2, xv.w + d3};
                    *(float4*)(os + 4 * i) = o;
                }
                if (part == 0) out_idx[grow] = (float)bi;
            }
        }
        // meta == 3: cleanup kernel writes this row (incl. its loss term)
    }

    for (int off = 32; off > 0; off >>= 1) lsum += __shfl_down(lsum, off, 64);
    if ((tid & 63) == 0) red[tid >> 6] = lsum;
    __syncthreads();
    if (tid == 0) {
        float s = (red[0] + red[1]) + (red[2] + red[3]);
        atomicAdd(out_loss, s * LOSS_SCALE);
    }
}

// Exact re-scan of flagged rows (bit-exact numerics). Hazard rows only.
#define CH 16
__global__ __launch_bounds__(256) void vq_cleanup(
        const float* __restrict__ x, const float* __restrict__ w,
        const float* __restrict__ e2,
        const unsigned* __restrict__ flag_cnt,
        const unsigned* __restrict__ flag_list,
        float* __restrict__ out_q, float* __restrict__ out_loss,
        float* __restrict__ out_idx) {
    __shared__ float xs[CH][68];
    __shared__ float wt[128][68];
    __shared__ float sx2[CH];
    const int tid = threadIdx.x;
    const int rowsub = tid >> 4;    // 0..15
    const int kslot = tid & 15;
    const unsigned cnt = *flag_cnt;

    for (unsigned base = blockIdx.x * CH; base < cnt; base += gridDim.x * CH) {
        const int nrows = (int)min((unsigned)CH, cnt - base);
        __syncthreads();
        {
            int rr = tid >> 4, sg = tid & 15;
            if (rr < nrows) {
                unsigned grow = flag_list[base + rr];
                *(float4*)&xs[rr][sg * 4] =
                    *(const float4*)(x + (size_t)grow * DIM + sg * 4);
            }
        }
        __syncthreads();
        if (tid < nrows) {
            float s = 0.f;
#pragma unroll
            for (int d = 0; d < DIM; ++d) s = fmaf(xs[tid][d], xs[tid][d], s);
            sx2[tid] = s;
        }

        unsigned long long kmin = ~0ULL;
        for (int tile = 0; tile < KCODES / 128; ++tile) {
            __syncthreads();
#pragma unroll
            for (int i = 0; i < 8; ++i) {
                int f = tid + i * 256;
                int code = f >> 4, sg = f & 15;
                *(float4*)&wt[code][sg * 4] =
                    *(const float4*)(w + (size_t)(tile * 128 + code) * DIM + sg * 4);
            }
            __syncthreads();
            if (rowsub < nrows) {
#pragma unroll
                for (int j = 0; j < 8; ++j) {
                    int cl = j * 16 + kslot;
                    int code = tile * 128 + cl;
                    float dot = 0.f;
#pragma unroll
                    for (int d4 = 0; d4 < 16; ++d4) {
                        float4 wv4 = *(const float4*)&wt[cl][d4 * 4];
                        float4 xv4 = *(const float4*)&xs[rowsub][d4 * 4];
                        dot = fmaf(wv4.x, xv4.x, dot);
                        dot = fmaf(wv4.y, xv4.y, dot);
                        dot = fmaf(wv4.z, xv4.z, dot);
                        dot = fmaf(wv4.w, xv4.w, dot);
                    }
                    float dist = (sx2[rowsub] + e2[code]) - 2.0f * dot;
                    unsigned long long key =
                        ((unsigned long long)__float_as_uint(dist) << 32) |
                        (unsigned)code;
                    kmin = kmin < key ? kmin : key;
                }
            }
        }
#pragma unroll
        for (int off = 1; off < 16; off <<= 1) {
            unsigned long long o = __shfl_xor(kmin, off, 64);
            kmin = kmin < o ? kmin : o;
        }
        if (rowsub < nrows) {
            int bi = (int)(unsigned)(kmin & 0xFFFFFFFFu);
            unsigned grow = flag_list[base + rowsub];
            float4 x4 = *(float4*)&xs[rowsub][kslot * 4];
            float4 w4 = *(const float4*)(w + (size_t)bi * DIM + kslot * 4);
            float d0 = w4.x - x4.x, d1 = w4.y - x4.y;
            float d2 = w4.z - x4.z, d3 = w4.w - x4.w;
            float ls = 0.f;
            ls = fmaf(d0, d0, ls);
            ls = fmaf(d1, d1, ls);
            ls = fmaf(d2, d2, ls);
            ls = fmaf(d3, d3, ls);
            float4 o = {x4.x + d0, x4.y + d1, x4.z + d2, x4.w + d3};
            *(float4*)(out_q + (size_t)grow * DIM + kslot * 4) = o;
            if (kslot == 0) out_idx[grow] = (float)bi;
#pragma unroll
            for (int off = 1; off < 16; off <<= 1)
                ls += __shfl_xor(ls, off, 64);
            if (kslot == 0) atomicAdd(out_loss, ls * LOSS_SCALE);
        }
    }
}

extern "C" void kernel_launch(void* const* d_in, const int* in_sizes, int n_in,
                              void* d_out, int out_size, void* d_ws, size_t ws_size,
                              hipStream_t stream) {
    const float* x = (const float*)d_in[0];   // [N, D]
    const float* w = (const float*)d_in[1];   // [K, D]

    float* out_q    = (float*)d_out;
    float* out_loss = (float*)d_out + (size_t)NROWS * DIM;
    float* out_idx  = out_loss + 1;

    // ws: e2 (4KB) | w_hi frag-order (128KB) | w_lo (128KB) | cnt | list (512KB)
    float* e2 = (float*)d_ws;
    short* w_hi = (short*)(e2 + KCODES);
    short* w_lo = w_hi + (size_t)KCODES * DIM;
    unsigned* cnt = (unsigned*)(w_lo + (size_t)KCODES * DIM);
    unsigned* list = cnt + 1;

    prep_w<<<(KCODES + 255) / 256, 256, 0, stream>>>(w, e2, w_hi, w_lo,
                                                     out_loss, cnt);
    vq_main<<<NROWS / 128, 256, 0, stream>>>(x, w, e2, w_hi, w_lo,
                                             out_q, out_loss, out_idx, cnt, list);
    vq_cleanup<<<256, 256, 0, stream>>>(x, w, e2, cnt, list,
                                        out_q, out_loss, out_idx);
}

// Round 9
// 179.872 us; speedup vs baseline: 1.1500x; 1.1412x over previous
//
#include <hip/hip_runtime.h>

// VectorQuantizer forward: N=131072 rows of D=64 vs K=1024 codes.
// Outputs flat fp32: [quantized_st (N*D), loss (1), indices-as-float (N)].
//
// Exactness scheme (validated round 6, absmax 0):
//  - vq_main: bf16 hi/lo split MFMA of g[k] = e2[k] - 2*dot. Per row, the
//    EXACT global top-4 (value,idx) is computed. Classification by the
//    validated MARGIN=5e-5 window around the best:
//      * 1 in-window              -> fast path (strict gap: order-independent)
//      * 2-3 in-window, no hazard -> inline exact re-check of candidates only
//      * hazards (4th in-window, two in-window candidates sharing an m-lane,
//        or x2>=120) -> block-local exact full-K re-scan (tail phase)
//
// Round 9: FUSE CLEANUP INTO vq_main. The flag of a hazard row is computed by
// its own block, so the cross-block flag list + third kernel were pure
// overhead. Each block now collects hazard rows in LDS (hcnt/hlist) and
// resolves them wave-per-row in a tail: full 1024-code exact scan, one lane
// per 16 codes; u64 (dist,idx) key-min is partition- and order-invariant so
// the argmin is exact under any lane mapping; x2/dot/loss fmaf chains mirror
// the old cleanup bit-for-bit. K-loop/classification = R6 exact (R7 per-wave
// and R8 per-block desync both null -> reverted; lockstep exonerated).
// KEPT: (-2*w) prepack, e2-folded-into-MFMA-C-init, memset merge, MARGIN 5e-5.

#define NROWS 131072
#define DIM 64
#define KCODES 1024
#define MARGIN 5e-5f
#define X2_GUARD 120.0f
#define LOSS_SCALE (1.25f / ((float)NROWS * (float)DIM))
#define PADID (1 << 20)

typedef short bf16x8 __attribute__((ext_vector_type(8)));
typedef float f32x4 __attribute__((ext_vector_type(4)));

__device__ __forceinline__ short f2bf(float f) {
    unsigned u = __float_as_uint(f);
    u += 0x7FFF + ((u >> 16) & 1);   // RNE
    return (short)(u >> 16);
}
__device__ __forceinline__ float bf2f(short h) {
    return __uint_as_float(((unsigned)(unsigned short)h) << 16);
}

// Per code k: e2[k] by sequential fmaf (bit-pattern the exact paths rely on),
// plus bf16 hi/lo split of (-2*w) stored in MFMA B-frag order:
//   short index = ((((t*2+ct)*2+kc)*4+q)*16 + m)*8 + j
//   where k = t*32 + ct*16 + m, d = kc*32 + q*8 + j.
// Thread k==0 also zeroes the loss accumulator.
__global__ __launch_bounds__(256) void prep_w(const float* __restrict__ w,
                                              float* __restrict__ e2,
                                              short* __restrict__ w_hi,
                                              short* __restrict__ w_lo,
                                              float* __restrict__ out_loss) {
    int k = blockIdx.x * blockDim.x + threadIdx.x;
    if (k == 0) *out_loss = 0.0f;
    if (k >= KCODES) return;
    const float* wk = w + (size_t)k * DIM;
    float r[DIM];
#pragma unroll
    for (int i = 0; i < DIM / 4; ++i) *(float4*)&r[4 * i] = *(const float4*)(wk + 4 * i);
    float s = 0.f;
#pragma unroll
    for (int d = 0; d < DIM; ++d) s = fmaf(r[d], r[d], s);
    e2[k] = s;

    const int t = k >> 5, ct = (k >> 4) & 1, m = k & 15;
#pragma unroll
    for (int kc = 0; kc < 2; ++kc)
#pragma unroll
        for (int q = 0; q < 4; ++q) {
            bf16x8 hv, lv;
#pragma unroll
            for (int j = 0; j < 8; ++j) {
                float f = -2.0f * r[kc * 32 + q * 8 + j];   // exact scale
                short h = f2bf(f);
                hv[j] = h;
                lv[j] = f2bf(f - bf2f(h));
            }
            size_t fo = ((size_t)(((t * 2 + ct) * 2 + kc) * 4 + q) * 16 + m) * 8;
            *(bf16x8*)(w_hi + fo) = hv;
            *(bf16x8*)(w_lo + fo) = lv;
        }
}

// compare-exchange / min-pair under (value, idx) lexicographic order
#define MINPAIR(av, ai, bv, bi)                                   \
    { bool tk_ = (bv < av) || (bv == av && bi < ai);              \
      av = tk_ ? bv : av; ai = tk_ ? bi : ai; }
#define CEX(xv, xi, yv, yi)                                       \
    { bool tk_ = (yv < xv) || (yv == xv && yi < xi);              \
      float tv_ = xv; int ti_ = xi;                               \
      xv = tk_ ? yv : xv; xi = tk_ ? yi : xi;                     \
      yv = tk_ ? tv_ : yv; yi = tk_ ? ti_ : yi; }

// Block: 4 waves x 32 rows = 128 rows. No LDS/barriers in the K-loop; B-frags
// are direct global b128 loads from the frag-ordered arrays.
__global__ __launch_bounds__(256, 3) void vq_main(
        const float* __restrict__ x, const float* __restrict__ w,
        const float* __restrict__ e2,
        const short* __restrict__ w_hi, const short* __restrict__ w_lo,
        float* __restrict__ out_q, float* __restrict__ out_loss,
        float* __restrict__ out_idx) {
    const int tid = threadIdx.x;
    const int lane = tid & 63;
    const int wv = tid >> 6;
    const int m = lane & 15;
    const int q = lane >> 4;
    const int block_row0 = blockIdx.x * 128;
    const int wave_row0 = block_row0 + wv * 32;

    __shared__ int sidx[128];
    __shared__ int scnd[128][2];
    __shared__ unsigned char sflg[128];   // 0 fast, 1 two-cand, 2 three-cand, 3 hazard
    __shared__ float red[4];
    __shared__ int hcnt;                  // block-local hazard list
    __shared__ short hlist[128];

    if (tid == 0) hcnt = 0;

    // ---- A operand: 2 rowtiles x 2 k-chunks; A[m][k=q*8+j] ----
    float xa[2][2][8];
#pragma unroll
    for (int rt = 0; rt < 2; ++rt) {
        const float* xr = x + (size_t)(wave_row0 + rt * 16 + m) * DIM + q * 8;
        *(float4*)&xa[rt][0][0] = *(const float4*)(xr);
        *(float4*)&xa[rt][0][4] = *(const float4*)(xr + 4);
        *(float4*)&xa[rt][1][0] = *(const float4*)(xr + 32);
        *(float4*)&xa[rt][1][4] = *(const float4*)(xr + 36);
    }
    bf16x8 ah[2][2], al[2][2];
#pragma unroll
    for (int rt = 0; rt < 2; ++rt)
#pragma unroll
        for (int c = 0; c < 2; ++c)
#pragma unroll
            for (int j = 0; j < 8; ++j) {
                float f = xa[rt][c][j];
                short h = f2bf(f);
                ah[rt][c][j] = h;
                al[rt][c][j] = f2bf(f - bf2f(h));
            }

    float best[2][4], sec[2][4];
    int bidx[2][4], sbix[2][4];
#pragma unroll
    for (int rt = 0; rt < 2; ++rt)
#pragma unroll
        for (int r = 0; r < 4; ++r) {
            best[rt][r] = 3.4e38f;
            sec[rt][r] = 3.4e38f;
            bidx[rt][r] = PADID;
            sbix[rt][r] = PADID;
        }

    __syncthreads();   // hcnt init visible before any append

    // Per-lane B pointers into frag-ordered arrays; tile stride 2048 shorts.
    const short* ph = w_hi + q * 128 + m * 8;
    const short* pl = w_lo + q * 128 + m * 8;
    const float* pe = e2 + m;

    for (int t = 0; t < KCODES / 32; ++t) {
        bf16x8 bh[2][2], bl[2][2];
#pragma unroll
        for (int ct = 0; ct < 2; ++ct)
#pragma unroll
            for (int kc = 0; kc < 2; ++kc) {
                int off = t * 2048 + (ct * 2 + kc) * 512;
                bh[ct][kc] = *(const bf16x8*)(ph + off);
                bl[ct][kc] = *(const bf16x8*)(pl + off);
            }
        float e2c0 = pe[t * 32];
        float e2c1 = pe[t * 32 + 16];

#pragma unroll
        for (int rt = 0; rt < 2; ++rt)
#pragma unroll
            for (int ct = 0; ct < 2; ++ct) {
                float ei = ct ? e2c1 : e2c0;
                f32x4 a = {ei, ei, ei, ei};
                a = __builtin_amdgcn_mfma_f32_16x16x32_bf16(al[rt][0], bh[ct][0], a, 0, 0, 0);
                a = __builtin_amdgcn_mfma_f32_16x16x32_bf16(ah[rt][0], bl[ct][0], a, 0, 0, 0);
                a = __builtin_amdgcn_mfma_f32_16x16x32_bf16(ah[rt][0], bh[ct][0], a, 0, 0, 0);
                a = __builtin_amdgcn_mfma_f32_16x16x32_bf16(al[rt][1], bh[ct][1], a, 0, 0, 0);
                a = __builtin_amdgcn_mfma_f32_16x16x32_bf16(ah[rt][1], bl[ct][1], a, 0, 0, 0);
                a = __builtin_amdgcn_mfma_f32_16x16x32_bf16(ah[rt][1], bh[ct][1], a, 0, 0, 0);
                int id = t * 32 + ct * 16 + m;
#pragma unroll
                for (int r = 0; r < 4; ++r) {
                    float g = a[r];
                    bool ltb = g < best[rt][r];
                    bool lts = g < sec[rt][r];
                    float nsec = ltb ? best[rt][r] : (lts ? g : sec[rt][r]);
                    int nsid = ltb ? bidx[rt][r] : (lts ? id : sbix[rt][r]);
                    best[rt][r] = ltb ? g : best[rt][r];
                    bidx[rt][r] = ltb ? id : bidx[rt][r];
                    sec[rt][r] = nsec;
                    sbix[rt][r] = nsid;
                }
            }
    }

    // ---- exact global top-4 per row via bitonic 4+4->4 merges over m-lanes ----
#pragma unroll
    for (int rt = 0; rt < 2; ++rt)
#pragma unroll
        for (int r = 0; r < 4; ++r) {
            float v0 = best[rt][r], v1 = sec[rt][r], v2 = 3.4e38f, v3 = 3.4e38f;
            int j0 = bidx[rt][r], j1 = sbix[rt][r], j2 = PADID, j3 = PADID;
#pragma unroll
            for (int off = 1; off < 16; off <<= 1) {
                float b0 = __shfl_xor(v0, off, 64);
                float b1 = __shfl_xor(v1, off, 64);
                float b2 = __shfl_xor(v2, off, 64);
                float b3 = __shfl_xor(v3, off, 64);
                int k0 = __shfl_xor(j0, off, 64);
                int k1 = __shfl_xor(j1, off, 64);
                int k2 = __shfl_xor(j2, off, 64);
                int k3 = __shfl_xor(j3, off, 64);
                // bitonic split: lows = min(a_i, b_{3-i}) == 4 smallest of union
                MINPAIR(v0, j0, b3, k3);
                MINPAIR(v1, j1, b2, k2);
                MINPAIR(v2, j2, b1, k1);
                MINPAIR(v3, j3, b0, k0);
                // sort the bitonic 4-list
                CEX(v0, j0, v2, j2);
                CEX(v1, j1, v3, j3);
                CEX(v0, j0, v1, j1);
                CEX(v2, j2, v3, j3);
            }
            if (m == 0) {
                bool w1 = v1 < v0 + MARGIN;
                bool w2 = v2 < v0 + MARGIN;
                bool w3 = v3 < v0 + MARGIN;
                bool samem = (w1 && ((j0 & 15) == (j1 & 15))) ||
                             (w2 && (((j0 & 15) == (j2 & 15)) ||
                                     ((j1 & 15) == (j2 & 15))));
                int meta;
                if (w3 || samem) meta = 3;
                else if (w2) meta = 2;
                else if (w1) meta = 1;
                else meta = 0;
                int lr = wv * 32 + rt * 16 + q * 4 + r;
                sidx[lr] = j0;
                scnd[lr][0] = j1;
                scnd[lr][1] = j2;
                sflg[lr] = (unsigned char)meta;
                if (meta == 3) {
                    int p = atomicAdd(&hcnt, 1);
                    hlist[p] = (short)lr;
                }
            }
        }
    __syncthreads();

    // ---- output pass: 2 x 64 rows, 4 threads/row ----
    float lsum = 0.f;
    const int rl = tid >> 2, part = tid & 3;
#pragma unroll
    for (int p = 0; p < 2; ++p) {
        int lr = p * 64 + rl;
        int grow = block_row0 + lr;
        int meta = sflg[lr];
        if (meta == 0) {
            int bi = sidx[lr];
            const float* xs = x + (size_t)grow * DIM + part * 16;
            const float* ws = w + (size_t)bi * DIM + part * 16;
            float* os = out_q + (size_t)grow * DIM + part * 16;
#pragma unroll
            for (int i = 0; i < 4; ++i) {
                float4 xv = *(const float4*)(xs + 4 * i);
                float4 wv4 = *(const float4*)(ws + 4 * i);
                float d0 = wv4.x - xv.x, d1 = wv4.y - xv.y;
                float d2 = wv4.z - xv.z, d3 = wv4.w - xv.w;
                lsum = fmaf(d0, d0, lsum);
                lsum = fmaf(d1, d1, lsum);
                lsum = fmaf(d2, d2, lsum);
                lsum = fmaf(d3, d3, lsum);
                float4 o = {xv.x + d0, xv.y + d1, xv.z + d2, xv.w + d3};
                *(float4*)(os + 4 * i) = o;
            }
            if (part == 0) out_idx[grow] = (float)bi;
        } else if (meta != 3) {
            // inline exact re-check among 2-3 candidates (cleanup numerics)
            int nc = meta + 1;
            int cand = (part == 0) ? sidx[lr]
                     : (part == 1) ? scnd[lr][0] : scnd[lr][1];
            unsigned long long key = ~0ULL;
            float x2v = 0.f;
            if (part < nc) {
                const float* xr = x + (size_t)grow * DIM;
                const float* wr = w + (size_t)cand * DIM;
                float dot = 0.f;
#pragma unroll
                for (int d4 = 0; d4 < 16; ++d4) {
                    float4 xv = *(const float4*)(xr + 4 * d4);
                    float4 wv4 = *(const float4*)(wr + 4 * d4);
                    x2v = fmaf(xv.x, xv.x, x2v);
                    x2v = fmaf(xv.y, xv.y, x2v);
                    x2v = fmaf(xv.z, xv.z, x2v);
                    x2v = fmaf(xv.w, xv.w, x2v);
                    dot = fmaf(xv.x, wv4.x, dot);
                    dot = fmaf(xv.y, wv4.y, dot);
                    dot = fmaf(xv.z, wv4.z, dot);
                    dot = fmaf(xv.w, wv4.w, dot);
                }
                float dist = (x2v + e2[cand]) - 2.0f * dot;
                key = ((unsigned long long)__float_as_uint(dist) << 32) |
                      (unsigned)cand;
            }
            {
                unsigned long long o1 = __shfl_xor(key, 1, 64);
                key = key < o1 ? key : o1;
                unsigned long long o2 = __shfl_xor(key, 2, 64);
                key = key < o2 ? key : o2;
            }
            float x2b = __shfl(x2v, lane & 60, 64);   // part0's x2 (part0<nc)
            if (x2b >= X2_GUARD) {
                if (part == 0) {
                    int pp = atomicAdd(&hcnt, 1);
                    hlist[pp] = (short)lr;     // route to block-local tail
                }
            } else {
                int bi = (int)(unsigned)(key & 0xFFFFFFFFu);
                const float* xs = x + (size_t)grow * DIM + part * 16;
                const float* ws = w + (size_t)bi * DIM + part * 16;
                float* os = out_q + (size_t)grow * DIM + part * 16;
#pragma unroll
                for (int i = 0; i < 4; ++i) {
                    float4 xv = *(const float4*)(xs + 4 * i);
                    float4 wv4 = *(const float4*)(ws + 4 * i);
                    float d0 = wv4.x - xv.x, d1 = wv4.y - xv.y;
                    float d2 = wv4.z - xv.z, d3 = wv4.w - xv.w;
                    lsum = fmaf(d0, d0, lsum);
                    lsum = fmaf(d1, d1, lsum);
                    lsum = fmaf(d2, d2, lsum);
                    lsum = fmaf(d3, d3, lsum);
                    float4 o = {xv.x + d0, xv.y + d1, xv.z + d2, xv.w + d3};
                    *(float4*)(os + 4 * i) = o;
                }
                if (part == 0) out_idx[grow] = (float)bi;
            }
        }
        // meta == 3: resolved by the tail below
    }

    for (int off = 32; off > 0; off >>= 1) lsum += __shfl_down(lsum, off, 64);
    if ((tid & 63) == 0) red[tid >> 6] = lsum;
    __syncthreads();   // red + all hlist appends visible past this point
    if (tid == 0) {
        float s = (red[0] + red[1]) + (red[2] + red[3]);
        atomicAdd(out_loss, s * LOSS_SCALE);
    }

    // ---- tail: block-local exact full-K re-scan of hazard rows ----
    // Wave-per-row; lane handles codes {jj*64+lane}. u64 (dist,idx) key-min is
    // partition/order-invariant -> exact argmin + numpy tie rule. x2/dot/loss
    // fmaf chains mirror the old cleanup kernel bit-for-bit.
    const int nh = hcnt;
    for (int h = wv; h < nh; h += 4) {
        const int lr = hlist[h];
        const int grow = block_row0 + lr;
        const float* xr = x + (size_t)grow * DIM;
        float4 xf[16];
#pragma unroll
        for (int i = 0; i < 16; ++i) xf[i] = *(const float4*)(xr + 4 * i);
        float x2 = 0.f;
#pragma unroll
        for (int i = 0; i < 16; ++i) {
            x2 = fmaf(xf[i].x, xf[i].x, x2);
            x2 = fmaf(xf[i].y, xf[i].y, x2);
            x2 = fmaf(xf[i].z, xf[i].z, x2);
            x2 = fmaf(xf[i].w, xf[i].w, x2);
        }
        unsigned long long kmin = ~0ULL;
        for (int jj = 0; jj < 16; ++jj) {
            int code = jj * 64 + lane;
            const float* wr = w + (size_t)code * DIM;
            float dot = 0.f;
#pragma unroll
            for (int d4 = 0; d4 < 16; ++d4) {
                float4 wv4 = *(const float4*)(wr + 4 * d4);
                dot = fmaf(wv4.x, xf[d4].x, dot);
                dot = fmaf(wv4.y, xf[d4].y, dot);
                dot = fmaf(wv4.z, xf[d4].z, dot);
                dot = fmaf(wv4.w, xf[d4].w, dot);
            }
            float dist = (x2 + e2[code]) - 2.0f * dot;
            unsigned long long key =
                ((unsigned long long)__float_as_uint(dist) << 32) |
                (unsigned)code;
            kmin = kmin < key ? kmin : key;
        }
#pragma unroll
        for (int off = 1; off < 64; off <<= 1) {
            unsigned long long o = __shfl_xor(kmin, off, 64);
            kmin = kmin < o ? kmin : o;
        }
        int bi = (int)(unsigned)(kmin & 0xFFFFFFFFu);
        float ls = 0.f;
        if (lane < 16) {
            float4 x4 = *(const float4*)(xr + 4 * lane);   // static-free reload
            float4 w4 = *(const float4*)(w + (size_t)bi * DIM + 4 * lane);
            float d0 = w4.x - x4.x, d1 = w4.y - x4.y;
            float d2 = w4.z - x4.z, d3 = w4.w - x4.w;
            ls = fmaf(d0, d0, ls);
            ls = fmaf(d1, d1, ls);
            ls = fmaf(d2, d2, ls);
            ls = fmaf(d3, d3, ls);
            float4 o = {x4.x + d0, x4.y + d1, x4.z + d2, x4.w + d3};
            *(float4*)(out_q + (size_t)grow * DIM + 4 * lane) = o;
            if (lane == 0) out_idx[grow] = (float)bi;
        }
#pragma unroll
        for (int off = 1; off < 16; off <<= 1)
            ls += __shfl_xor(ls, off, 64);
        if (lane == 0) atomicAdd(out_loss, ls * LOSS_SCALE);
    }
}

extern "C" void kernel_launch(void* const* d_in, const int* in_sizes, int n_in,
                              void* d_out, int out_size, void* d_ws, size_t ws_size,
                              hipStream_t stream) {
    const float* x = (const float*)d_in[0];   // [N, D]
    const float* w = (const float*)d_in[1];   // [K, D]

    float* out_q    = (float*)d_out;
    float* out_loss = (float*)d_out + (size_t)NROWS * DIM;
    float* out_idx  = out_loss + 1;

    // ws: e2 (4KB) | w_hi frag-order (128KB) | w_lo (128KB)
    float* e2 = (float*)d_ws;
    short* w_hi = (short*)(e2 + KCODES);
    short* w_lo = w_hi + (size_t)KCODES * DIM;

    prep_w<<<(KCODES + 255) / 256, 256, 0, stream>>>(w, e2, w_hi, w_lo, out_loss);
    vq_main<<<NROWS / 128, 256, 0, stream>>>(x, w, e2, w_hi, w_lo,
                                             out_q, out_loss, out_idx);
}